// Round 2
// baseline (72.848 us; speedup 1.0000x reference)
//
#include <hip/hip_runtime.h>

#define N_CAMP 50
#define DAYS   365
#define BASIS  1e-10f
#define BATCH  4096
#define NTHR   384

// One block per batch element b. Thread t computes day d = t (t < 365),
// writes its 9 Q-entries into LDS, then the block does a fully-coalesced
// cooperative write-out of the contiguous 365*9-float region.
__global__ __launch_bounds__(NTHR)
void transition_prob_kernel(const float* __restrict__ adstock,
                            const float* __restrict__ mu,
                            const float* __restrict__ beta,
                            float* __restrict__ out)
{
    __shared__ float sb0[N_CAMP];
    __shared__ float sb1[N_CAMP];
    __shared__ float sb2[N_CAMP];
    __shared__ float smu[3];
    __shared__ float sQ[DAYS * 9];   // 13140 B

    const int tid = threadIdx.x;
    const int b   = blockIdx.x;

    // Stage beta (150 floats) and mu (3 floats) in LDS.
    if (tid < 3 * N_CAMP) {
        const int c = tid / 3;
        const int k = tid % 3;
        const float v = beta[tid];
        if (k == 0) sb0[c] = v;
        else if (k == 1) sb1[c] = v;
        else sb2[c] = v;
    }
    if (tid < 3) smu[tid] = mu[tid];
    __syncthreads();

    const int d = tid;
    if (d < DAYS) {
        const float* arow = adstock + (size_t)b * (N_CAMP * (DAYS + 1)) + (d + 1);

        float o1 = 0.f, o2 = 0.f, o3 = 0.f;
#pragma unroll 10
        for (int c = 0; c < N_CAMP; ++c) {
            const float a = arow[(size_t)c * (DAYS + 1)];
            o1 = fmaf(a, sb0[c], o1);
            o2 = fmaf(a, sb1[c], o2);
            o3 = fmaf(a, sb2[c], o3);
        }

        const float e1 = expf(smu[0] + o1);
        const float e2 = expf(smu[1] + o2);
        const float e3 = expf(smu[2] + o3);
        const float inv0 = 1.0f / (1.0f + e1);
        const float inv1 = 1.0f / (1.0f + e2 + e3);

        // stride-9 LDS writes across consecutive lanes: gcd(9,32)=1 ->
        // exactly 2-way bank aliasing for a wave64 = free.
        float* q = &sQ[d * 9];
        q[0] = fmaxf(inv0,      BASIS);  // Q00
        q[1] = fmaxf(e1 * inv0, BASIS);  // Q01
        q[2] = BASIS;                    // Q02
        q[3] = fmaxf(e2 * inv1, BASIS);  // Q10
        q[4] = fmaxf(inv1,      BASIS);  // Q11
        q[5] = fmaxf(e3 * inv1, BASIS);  // Q12
        q[6] = BASIS;                    // Q20
        q[7] = BASIS;                    // Q21
        q[8] = 1.0f;                     // Q22
    }
    __syncthreads();

    // Coalesced write-out: each store instruction covers 256 B of full lines.
    float* dst = out + (size_t)b * (DAYS * 9);
#pragma unroll
    for (int i = tid; i < DAYS * 9; i += NTHR) {
        dst[i] = sQ[i];
    }
}

__global__ void scalar_tail_kernel(const float* __restrict__ init_prob,
                                   const float* __restrict__ click_prob,
                                   float* __restrict__ out)
{
    const size_t base = (size_t)BATCH * DAYS * 9;
    if (threadIdx.x == 0) {
        out[base + 0] = 1.0f / (1.0f + expf(-init_prob[0]));
        out[base + 1] = 1.0f / (1.0f + expf(-click_prob[0]));
    }
}

extern "C" void kernel_launch(void* const* d_in, const int* in_sizes, int n_in,
                              void* d_out, int out_size, void* d_ws, size_t ws_size,
                              hipStream_t stream)
{
    const float* adstock    = (const float*)d_in[0];
    const float* mu         = (const float*)d_in[1];
    const float* beta       = (const float*)d_in[2];
    const float* init_prob  = (const float*)d_in[3];
    const float* click_prob = (const float*)d_in[4];
    float* out = (float*)d_out;

    transition_prob_kernel<<<dim3(BATCH), dim3(NTHR), 0, stream>>>(adstock, mu, beta, out);
    scalar_tail_kernel<<<1, 64, 0, stream>>>(init_prob, click_prob, out);
}